// Round 8
// baseline (15.039 us; speedup 1.0000x reference)
//
#include <hip/hip_runtime.h>

// GraphVolterraLayer: N_S=64, N_T=32, N_EFF=2048, K_T1=K_T2=8, BATCH=16.
// One kernel, grid 256 = (b, iT-pair), 512 threads (8 waves).
// Fixed phases (8-wave): T1 = UG^T S_b  ->  shat = T1 UPT   (MFMA 3-term hi/lo)
// Per-iT "sides" (4 waves each, side = w>>2):
//   Gm/A/Q = shat x {wGm,wA,wQ}; wv = rowreduce(h1c .* Q)
//   E = HS .* (A Gm^T) -> bf16 hi XOR-swz;  z1 = UG^T wv (exact fp32)
//   F = E UG^T (MFMA hi-only); z2[iS] = sum_kS UG[iS,kS] F[kS,iS]
// mfma: D[row][col] = sum_k A[row][k]*B[col][k]; D-layout col=l&15,
// row=4*(l>>4)+reg (m89; validated on-problem r6/r7).

typedef short  bf16x8 __attribute__((ext_vector_type(8)));
typedef float  f32x4  __attribute__((ext_vector_type(4)));
typedef unsigned short u16;

static __device__ __forceinline__ u16 f2bf(float f) {
  unsigned u = __float_as_uint(f);
  u = (u + 0x7fff + ((u >> 16) & 1)) >> 16;    // RNE
  return (u16)u;
}
static __device__ __forceinline__ float bf2f(u16 h) {
  return __uint_as_float(((unsigned)h) << 16);
}
static __device__ __forceinline__ float dot4(f32x4 a, f32x4 b) {
  return a.x * b.x + a.y * b.y + a.z * b.z + a.w * b.w;
}

__global__ __launch_bounds__(512) void volterra_one(
    const float* __restrict__ s, const float* __restrict__ UG,
    const float* __restrict__ UPT, const float* __restrict__ h0,
    const float* __restrict__ h1c, const float* __restrict__ HS,
    const float* __restrict__ Hc, float* __restrict__ out)
{
  const int b   = blockIdx.x >> 4;
  const int iT0 = (blockIdx.x & 15) << 1;
  const int t   = threadIdx.x;
  const int w   = t >> 6;            // wave 0..7
  const int l   = t & 63;
  const int r   = l & 15;
  const int g   = l >> 4;

  __shared__ __align__(16) float sS[64][36];      // S_b, then shat
  __shared__ __align__(16) float sT1[64][36];
  __shared__ __align__(16) u16   sUGh[4096];      // UG bf16 hi, XOR-swz
  __shared__ __align__(16) u16   sUPTTh[32 * 40]; // UPT^T hi
  __shared__ __align__(16) u16   sUPTTl[32 * 40]; // UPT^T lo
  __shared__ __align__(16) float sUPT[32][36];
  __shared__ __align__(16) float sHS[64][68];
  __shared__ float sUhc[32 * 9];
  __shared__ __align__(16) float wGm[2][8 * 36], wA[2][8 * 36], wQ[2][8 * 36];
  __shared__ __align__(16) float sGm[2][64][12], sA[2][64][12];
  __shared__ __align__(16) u16   sE[2][4096];
  __shared__ float wv[2][64];
  __shared__ float zp1[2][4][64];
  __shared__ float zpart[2][4][64];

  // ---- P0: stage (float4) ----
  {
    const f32x4 v = ((const f32x4*)(s + b * 2048))[t];
    *(f32x4*)&sS[t >> 3][(t & 7) * 4] = v;
  }
  #pragma unroll
  for (int o4 = t, it = 0; it < 2; ++it, o4 += 512) {
    const int rr = o4 >> 4, c0 = (o4 & 15) * 4;
    const f32x4 v = ((const f32x4*)UG)[o4];
    short4 h;
    h.x = (short)f2bf(v.x); h.y = (short)f2bf(v.y);
    h.z = (short)f2bf(v.z); h.w = (short)f2bf(v.w);
    *(short4*)&sUGh[rr * 64 + (c0 ^ ((rr & 7) << 3))] = h;
  }
  #pragma unroll
  for (int o4 = t, it = 0; it < 2; ++it, o4 += 512) {
    const int rr = o4 >> 4, c0 = (o4 & 15) * 4;
    *(f32x4*)&sHS[rr][c0] = ((const f32x4*)HS)[o4];
  }
  if (t < 256) {
    const int k = t >> 3, c4 = t & 7;
    const f32x4 v = ((const f32x4*)UPT)[t];
    *(f32x4*)&sUPT[k][c4 * 4] = v;
    float arr[4] = {v.x, v.y, v.z, v.w};
    #pragma unroll
    for (int i = 0; i < 4; ++i) {
      const int c = 4 * c4 + i;
      const u16 hi = f2bf(arr[i]);
      sUPTTh[c * 40 + k] = hi;
      sUPTTl[c * 40 + k] = f2bf(arr[i] - bf2f(hi));
    }
    const int p = t & 7;               // uhc[k][p] = sum_q UPT[k,q] Hc[q,p]
    float a = 0.f;
    #pragma unroll
    for (int q = 0; q < 8; ++q) a += UPT[k * 32 + q] * Hc[q * 8 + p];
    sUhc[k * 9 + p] = a;
  }
  __syncthreads();

  // ---- P1: per-side weights (VALU) + T1 = UG^T S (8 wave-tiles) ----
  {
    const int side = t >> 8, p = (t >> 5) & 7, k = t & 31;
    const int iTs = iT0 + side;
    const float m1 = sUPT[iTs][k];
    const float m3 = sUPT[k][iTs];
    const float m2 = sUPT[k][p];
    wGm[side][p * 36 + k] = m1 * m2;
    wA [side][p * 36 + k] = m1 * sUhc[k * 9 + p];
    wQ [side][p * 36 + k] = m3 * m2;
  }
  {
    const int band = w >> 1, ct = w & 1;
    f32x4 acc = {0.f, 0.f, 0.f, 0.f};
    #pragma unroll
    for (int kc = 0; kc < 2; ++kc) {
      float av[8], bv[8];
      #pragma unroll
      for (int j = 0; j < 8; ++j)
        av[j] = UG[(kc * 32 + g * 8 + j) * 64 + 16 * band + r];
      #pragma unroll
      for (int j = 0; j < 8; ++j)
        bv[j] = sS[kc * 32 + g * 8 + j][ct * 16 + r];
      bf16x8 Ah, Al, Bh, Bl;
      #pragma unroll
      for (int j = 0; j < 8; ++j) {
        u16 h = f2bf(av[j]);
        Ah[j] = (short)h; Al[j] = (short)f2bf(av[j] - bf2f(h));
        h = f2bf(bv[j]);
        Bh[j] = (short)h; Bl[j] = (short)f2bf(bv[j] - bf2f(h));
      }
      acc = __builtin_amdgcn_mfma_f32_16x16x32_bf16(Ah, Bh, acc, 0, 0, 0);
      acc = __builtin_amdgcn_mfma_f32_16x16x32_bf16(Ah, Bl, acc, 0, 0, 0);
      acc = __builtin_amdgcn_mfma_f32_16x16x32_bf16(Al, Bh, acc, 0, 0, 0);
    }
    #pragma unroll
    for (int reg = 0; reg < 4; ++reg)
      sT1[16 * band + 4 * g + reg][ct * 16 + r] = acc[reg];
  }
  __syncthreads();

  // ---- P2: shat = T1 @ UPT (8 wave-tiles) -> overwrite sS ----
  {
    const int band = w >> 1, ct = w & 1;
    const f32x4 a0 = *(const f32x4*)&sT1[16 * band + r][g * 8];
    const f32x4 a1 = *(const f32x4*)&sT1[16 * band + r][g * 8 + 4];
    float av[8] = {a0.x, a0.y, a0.z, a0.w, a1.x, a1.y, a1.z, a1.w};
    bf16x8 Ah, Al;
    #pragma unroll
    for (int j = 0; j < 8; ++j) {
      const u16 h = f2bf(av[j]);
      Ah[j] = (short)h; Al[j] = (short)f2bf(av[j] - bf2f(h));
    }
    const bf16x8 Bh = *(const bf16x8*)&sUPTTh[(ct * 16 + r) * 40 + g * 8];
    const bf16x8 Bl = *(const bf16x8*)&sUPTTl[(ct * 16 + r) * 40 + g * 8];
    f32x4 acc = {0.f, 0.f, 0.f, 0.f};
    acc = __builtin_amdgcn_mfma_f32_16x16x32_bf16(Ah, Bh, acc, 0, 0, 0);
    acc = __builtin_amdgcn_mfma_f32_16x16x32_bf16(Ah, Bl, acc, 0, 0, 0);
    acc = __builtin_amdgcn_mfma_f32_16x16x32_bf16(Al, Bh, acc, 0, 0, 0);
    #pragma unroll
    for (int reg = 0; reg < 4; ++reg)
      sS[16 * band + 4 * g + reg][ct * 16 + r] = acc[reg];
  }
  __syncthreads();

  // ---- P3a: per-side Gm/A/Q triple-dot + wv shuffle-reduce ----
  {
    const int side = t >> 8, ts = t & 255;
    const int kSa = ts >> 3, p = ts & 7;
    float g0 = 0.f, g1v = 0.f, a0 = 0.f, a1v = 0.f, q0 = 0.f, q1v = 0.f;
    #pragma unroll
    for (int c4 = 0; c4 < 8; ++c4) {
      const f32x4 w1 = *(const f32x4*)&wGm[side][p * 36 + c4 * 4];
      const f32x4 w2 = *(const f32x4*)&wA [side][p * 36 + c4 * 4];
      const f32x4 w3 = *(const f32x4*)&wQ [side][p * 36 + c4 * 4];
      const f32x4 x0 = *(const f32x4*)&sS[kSa][c4 * 4];
      const f32x4 x1 = *(const f32x4*)&sS[kSa + 32][c4 * 4];
      g0  += dot4(x0, w1); a0  += dot4(x0, w2); q0  += dot4(x0, w3);
      g1v += dot4(x1, w1); a1v += dot4(x1, w2); q1v += dot4(x1, w3);
    }
    sGm[side][kSa][p] = g0; sGm[side][kSa + 32][p] = g1v;
    sA [side][kSa][p] = a0; sA [side][kSa + 32][p] = a1v;
    float wv0 = h1c[kSa * 8 + p] * q0;
    float wv1 = h1c[(kSa + 32) * 8 + p] * q1v;
    wv0 += __shfl_xor(wv0, 1); wv0 += __shfl_xor(wv0, 2); wv0 += __shfl_xor(wv0, 4);
    wv1 += __shfl_xor(wv1, 1); wv1 += __shfl_xor(wv1, 2); wv1 += __shfl_xor(wv1, 4);
    if (p == 0) { wv[side][kSa] = wv0; wv[side][kSa + 32] = wv1; }
  }
  __syncthreads();

  // ---- P3b: per-side E = HS .* (A Gm^T) -> bf16 swz ; z1 partials ----
  {
    const int side = t >> 8, sub = (t >> 6) & 3;
    const f32x4 gr0 = *(const f32x4*)&sGm[side][l][0];
    const f32x4 gr1 = *(const f32x4*)&sGm[side][l][4];
    #pragma unroll 4
    for (int j = 0; j < 16; ++j) {
      const int kS = 4 * j + sub;                    // wave-uniform
      const f32x4 a0v = *(const f32x4*)&sA[side][kS][0];
      const f32x4 a1v = *(const f32x4*)&sA[side][kS][4];
      const float e = (dot4(a0v, gr0) + dot4(a1v, gr1)) * sHS[kS][l];
      sE[side][kS * 64 + (l ^ ((kS & 7) << 3))] = f2bf(e);
    }
    const float wvl = wv[side][l];
    float part = 0.f;
    #pragma unroll
    for (int j = 0; j < 16; ++j) {
      const int kk = 16 * sub + j;
      part += __shfl(wvl, kk) * UG[kk * 64 + l];     // exact fp32, L2
    }
    zp1[side][sub][l] = part;
  }
  __syncthreads();

  // ---- P4: per-side F = E UG^T (MFMA hi-only); fuse z2 ----
  {
    const int side = t >> 8, sub = (t >> 6) & 3;
    f32x4 acc[4];
    #pragma unroll
    for (int nt = 0; nt < 4; ++nt) acc[nt] = (f32x4){0.f, 0.f, 0.f, 0.f};
    #pragma unroll
    for (int ks = 0; ks < 2; ++ks) {
      const int kcol = g * 8 + ks * 32;
      const int rowA = 16 * sub + r;
      const bf16x8 ah = *(const bf16x8*)&sE[side][rowA * 64 + (kcol ^ ((rowA & 7) << 3))];
      #pragma unroll
      for (int nt = 0; nt < 4; ++nt) {
        const int rowB = 16 * nt + r;
        const bf16x8 bh = *(const bf16x8*)&sUGh[rowB * 64 + (kcol ^ ((rowB & 7) << 3))];
        acc[nt] = __builtin_amdgcn_mfma_f32_16x16x32_bf16(ah, bh, acc[nt], 0, 0, 0);
      }
    }
    #pragma unroll
    for (int nt = 0; nt < 4; ++nt) {
      float zp = 0.f;
      #pragma unroll
      for (int reg = 0; reg < 4; ++reg) {
        const int kS = 16 * sub + 4 * g + reg;
        const int iS = 16 * nt + r;
        zp += bf2f(sUGh[iS * 64 + (kS ^ ((iS & 7) << 3))]) * acc[nt][reg];
      }
      zp += __shfl_xor(zp, 16);
      zp += __shfl_xor(zp, 32);
      if (g == 0) zpart[side][sub][16 * nt + r] = zp;
    }
  }
  __syncthreads();

  // ---- P5: combine + write ----
  if (t < 128) {
    const int side = t >> 6, c = t & 63;
    const float z2 = zpart[side][0][c] + zpart[side][1][c] +
                     zpart[side][2][c] + zpart[side][3][c];
    const float z1 = zp1[side][0][c] + zp1[side][1][c] +
                     zp1[side][2][c] + zp1[side][3][c];
    const int col = c * 32 + iT0 + side;
    out[b * 2048 + col] = h0[col] + z1 + z2;
  }
}

extern "C" void kernel_launch(void* const* d_in, const int* in_sizes, int n_in,
                              void* d_out, int out_size, void* d_ws, size_t ws_size,
                              hipStream_t stream) {
  const float* s   = (const float*)d_in[0];  // (16,2048)
  const float* UG  = (const float*)d_in[1];  // (64,64)
  const float* UPT = (const float*)d_in[2];  // (32,32)
  const float* h0  = (const float*)d_in[3];  // (2048,)
  const float* h1c = (const float*)d_in[4];  // (64,8)
  const float* HS  = (const float*)d_in[5];  // (64,64)
  const float* Hc  = (const float*)d_in[6];  // (8,8)
  float* out = (float*)d_out;

  volterra_one<<<256, 512, 0, stream>>>(s, UG, UPT, h0, h1c, HS, Hc, out);
}

// Round 9
// 13.714 us; speedup vs baseline: 1.0966x; 1.0966x over previous
//
#include <hip/hip_runtime.h>

// GraphVolterraLayer: N_S=64, N_T=32, N_EFF=2048, K_T1=K_T2=8, BATCH=16.
// One kernel, grid 256 = (b, iT-pair), 512 threads (8 waves), 5 barriers.
//
//  P0: stage S^T/UG^T bf16 hi/lo (swz), UG hi (swz), HS, UPT f32;
//      raw per-side weights from global:
//        wGmR[p][k]=UPT[iT,k]UPT[k,p]; wAR=UPT[iT,k]uhc[k][p]; wQR=UPT[k,iT]UPT[k,p]
//  P1: T1 = UG^T S (MFMA 3-term hi/lo, LDS frags)
//      + weight fold w'[p][j] = sum_k UPT[j,k] wR[p][k]   (shat GEMM eliminated:
//        Gm = (T1 UPT) wGm = T1 wGm')
//  P3a: Gm/A/Q = T1 x {wGm',wA',wQ'} fp32; wv = rowreduce(h1c .* Q)
//  P3b: E = HS .* (A Gm^T) -> bf16 hi XOR-swz; z1 partials = UG^T wv (fp32)
//  P4: F = E UG^T (MFMA hi-only); z2[iS] = sum_kS UG[iS,kS] F[kS,iS]
//  P5: out = h0 + z1 + z2
// mfma: D[row][col] = sum_k A[row][k]*B[col][k]; D-layout col=l&15,
// row=4*(l>>4)+reg (m89; validated on-problem r6-r8).

typedef short  bf16x8 __attribute__((ext_vector_type(8)));
typedef float  f32x4  __attribute__((ext_vector_type(4)));
typedef unsigned short u16;

static __device__ __forceinline__ u16 f2bf(float f) {
  unsigned u = __float_as_uint(f);
  u = (u + 0x7fff + ((u >> 16) & 1)) >> 16;    // RNE
  return (u16)u;
}
static __device__ __forceinline__ float bf2f(u16 h) {
  return __uint_as_float(((unsigned)h) << 16);
}
static __device__ __forceinline__ float dot4(f32x4 a, f32x4 b) {
  return a.x * b.x + a.y * b.y + a.z * b.z + a.w * b.w;
}

__global__ __launch_bounds__(512) void volterra_one(
    const float* __restrict__ s, const float* __restrict__ UG,
    const float* __restrict__ UPT, const float* __restrict__ h0,
    const float* __restrict__ h1c, const float* __restrict__ HS,
    const float* __restrict__ Hc, float* __restrict__ out)
{
  const int b   = blockIdx.x >> 4;
  const int iT0 = (blockIdx.x & 15) << 1;
  const int t   = threadIdx.x;
  const int w   = t >> 6;            // wave 0..7
  const int l   = t & 63;
  const int r   = l & 15;
  const int g   = l >> 4;

  __shared__ __align__(16) u16   sSTh[2048], sSTl[2048];   // S^T [32][64] swz
  __shared__ __align__(16) u16   sUGTh[4096], sUGTl[4096]; // UG^T [64][64] swz
  __shared__ __align__(16) u16   sUGh[4096];               // UG [64][64] swz hi
  __shared__ __align__(16) float sUPT[32][36];
  __shared__ __align__(16) float sHS[64][68];
  __shared__ __align__(16) float wGmR[2][288], wAR[2][288], wQR[2][288];
  __shared__ __align__(16) float wGmP[2][288], wAP[2][288], wQP[2][288];
  __shared__ __align__(16) float sT1[64][36];
  __shared__ __align__(16) float sGm[2][64][12], sA[2][64][12];
  __shared__ __align__(16) u16   sE[2][4096];
  __shared__ float wv[2][64];
  __shared__ float zp1[2][4][64], zpart[2][4][64];

  // ---- P0: stage ----
  {  // S^T bf16 hi/lo, chunk-XOR swizzled
    const f32x4 v = ((const f32x4*)(s + b * 2048))[t];
    const int rr = t >> 3, c0 = (t & 7) * 4;
    const float arr[4] = {v.x, v.y, v.z, v.w};
    #pragma unroll
    for (int i = 0; i < 4; ++i) {
      const int c = c0 + i;
      const u16 hi = f2bf(arr[i]);
      const int ad = c * 64 + (((rr >> 3) ^ (c & 7)) << 3) + (rr & 7);
      sSTh[ad] = hi;
      sSTl[ad] = f2bf(arr[i] - bf2f(hi));
    }
  }
  #pragma unroll
  for (int it = 0; it < 2; ++it) {   // UG: row-major hi + transposed hi/lo
    const int o4 = t + it * 512;
    const int rr = o4 >> 4, c0 = (o4 & 15) * 4;
    const f32x4 v = ((const f32x4*)UG)[o4];
    const float arr[4] = {v.x, v.y, v.z, v.w};
    short4 h4;
    h4.x = (short)f2bf(v.x); h4.y = (short)f2bf(v.y);
    h4.z = (short)f2bf(v.z); h4.w = (short)f2bf(v.w);
    *(short4*)&sUGh[rr * 64 + (c0 ^ ((rr & 7) << 3))] = h4;
    #pragma unroll
    for (int i = 0; i < 4; ++i) {
      const int c = c0 + i;
      const u16 hi = f2bf(arr[i]);
      const int ad = c * 64 + (((rr >> 3) ^ (c & 7)) << 3) + (rr & 7);
      sUGTh[ad] = hi;
      sUGTl[ad] = f2bf(arr[i] - bf2f(hi));
    }
  }
  #pragma unroll
  for (int it = 0; it < 2; ++it) {   // HS
    const int o4 = t + it * 512;
    *(f32x4*)&sHS[o4 >> 4][(o4 & 15) * 4] = ((const f32x4*)HS)[o4];
  }
  if (t < 256) {                     // UPT fp32
    *(f32x4*)&sUPT[t >> 3][(t & 7) * 4] = ((const f32x4*)UPT)[t];
  }
  {                                  // raw per-side weights (global reads only)
    const int side = t >> 8, p = (t >> 5) & 7, k = t & 31;
    const int iTs = iT0 + side;
    const float m1 = UPT[iTs * 32 + k];
    const float m3 = UPT[k * 32 + iTs];
    const float m2 = UPT[k * 32 + p];
    float uh = 0.f;
    #pragma unroll
    for (int q = 0; q < 8; ++q) uh += UPT[k * 32 + q] * Hc[q * 8 + p];
    wGmR[side][p * 36 + k] = m1 * m2;
    wAR [side][p * 36 + k] = m1 * uh;
    wQR [side][p * 36 + k] = m3 * m2;
  }
  __syncthreads();

  // ---- P1: T1 = UG^T S (8 wave-tiles, LDS b128 frags) + weight fold ----
  {
    const int band = w >> 1, ct = w & 1;
    const int rowA = 16 * band + r, rowB = ct * 16 + r;
    f32x4 acc = {0.f, 0.f, 0.f, 0.f};
    #pragma unroll
    for (int kc = 0; kc < 2; ++kc) {
      const int ch = kc * 4 + g;
      const int oa = rowA * 64 + ((ch ^ (rowA & 7)) << 3);
      const int ob = rowB * 64 + ((ch ^ (rowB & 7)) << 3);
      const bf16x8 Ah = *(const bf16x8*)&sUGTh[oa];
      const bf16x8 Al = *(const bf16x8*)&sUGTl[oa];
      const bf16x8 Bh = *(const bf16x8*)&sSTh[ob];
      const bf16x8 Bl = *(const bf16x8*)&sSTl[ob];
      acc = __builtin_amdgcn_mfma_f32_16x16x32_bf16(Ah, Bh, acc, 0, 0, 0);
      acc = __builtin_amdgcn_mfma_f32_16x16x32_bf16(Ah, Bl, acc, 0, 0, 0);
      acc = __builtin_amdgcn_mfma_f32_16x16x32_bf16(Al, Bh, acc, 0, 0, 0);
    }
    #pragma unroll
    for (int reg = 0; reg < 4; ++reg)
      sT1[16 * band + 4 * g + reg][ct * 16 + r] = acc[reg];
  }
  {  // w'[p][j] = sum_k UPT[j,k] * wR[p][k]   (VALU, overlaps MFMA)
    const int side = t >> 8, p = (t >> 5) & 7, j = t & 31;
    float aG = 0.f, aA = 0.f, aQ = 0.f;
    #pragma unroll
    for (int k4 = 0; k4 < 8; ++k4) {
      const f32x4 u  = *(const f32x4*)&sUPT[j][k4 * 4];
      const f32x4 w1 = *(const f32x4*)&wGmR[side][p * 36 + k4 * 4];
      const f32x4 w2 = *(const f32x4*)&wAR [side][p * 36 + k4 * 4];
      const f32x4 w3 = *(const f32x4*)&wQR [side][p * 36 + k4 * 4];
      aG += dot4(u, w1); aA += dot4(u, w2); aQ += dot4(u, w3);
    }
    wGmP[side][p * 36 + j] = aG;
    wAP [side][p * 36 + j] = aA;
    wQP [side][p * 36 + j] = aQ;
  }
  __syncthreads();

  // ---- P3a: Gm/A/Q = T1 x w' (fp32) + wv shuffle-reduce ----
  {
    const int side = t >> 8, ts = t & 255;
    const int kSa = ts >> 3, p = ts & 7;
    float g0 = 0.f, g1v = 0.f, a0 = 0.f, a1v = 0.f, q0 = 0.f, q1v = 0.f;
    #pragma unroll
    for (int c4 = 0; c4 < 8; ++c4) {
      const f32x4 w1 = *(const f32x4*)&wGmP[side][p * 36 + c4 * 4];
      const f32x4 w2 = *(const f32x4*)&wAP [side][p * 36 + c4 * 4];
      const f32x4 w3 = *(const f32x4*)&wQP [side][p * 36 + c4 * 4];
      const f32x4 x0 = *(const f32x4*)&sT1[kSa][c4 * 4];
      const f32x4 x1 = *(const f32x4*)&sT1[kSa + 32][c4 * 4];
      g0  += dot4(x0, w1); a0  += dot4(x0, w2); q0  += dot4(x0, w3);
      g1v += dot4(x1, w1); a1v += dot4(x1, w2); q1v += dot4(x1, w3);
    }
    sGm[side][kSa][p] = g0; sGm[side][kSa + 32][p] = g1v;
    sA [side][kSa][p] = a0; sA [side][kSa + 32][p] = a1v;
    float wv0 = h1c[kSa * 8 + p] * q0;
    float wv1 = h1c[(kSa + 32) * 8 + p] * q1v;
    wv0 += __shfl_xor(wv0, 1); wv0 += __shfl_xor(wv0, 2); wv0 += __shfl_xor(wv0, 4);
    wv1 += __shfl_xor(wv1, 1); wv1 += __shfl_xor(wv1, 2); wv1 += __shfl_xor(wv1, 4);
    if (p == 0) { wv[side][kSa] = wv0; wv[side][kSa + 32] = wv1; }
  }
  __syncthreads();

  // ---- P3b: E = HS .* (A Gm^T) -> bf16 swz ; z1 partials ----
  {
    const int side = t >> 8, sub = (t >> 6) & 3;
    const f32x4 gr0 = *(const f32x4*)&sGm[side][l][0];
    const f32x4 gr1 = *(const f32x4*)&sGm[side][l][4];
    #pragma unroll 4
    for (int j = 0; j < 16; ++j) {
      const int kS = 4 * j + sub;                    // wave-uniform
      const f32x4 a0v = *(const f32x4*)&sA[side][kS][0];
      const f32x4 a1v = *(const f32x4*)&sA[side][kS][4];
      const float e = (dot4(a0v, gr0) + dot4(a1v, gr1)) * sHS[kS][l];
      sE[side][kS * 64 + (l ^ ((kS & 7) << 3))] = f2bf(e);
    }
    const float wvl = wv[side][l];
    float part = 0.f;
    #pragma unroll
    for (int j = 0; j < 16; ++j) {
      const int kk = 16 * sub + j;
      part += __shfl(wvl, kk) * UG[kk * 64 + l];     // exact fp32, L2-hot
    }
    zp1[side][sub][l] = part;
  }
  __syncthreads();

  // ---- P4: F = E UG^T (MFMA hi-only); fuse z2 ----
  {
    const int side = t >> 8, sub = (t >> 6) & 3;
    f32x4 acc[4];
    #pragma unroll
    for (int nt = 0; nt < 4; ++nt) acc[nt] = (f32x4){0.f, 0.f, 0.f, 0.f};
    #pragma unroll
    for (int ks = 0; ks < 2; ++ks) {
      const int kcol = g * 8 + ks * 32;
      const int rowA = 16 * sub + r;
      const bf16x8 ah = *(const bf16x8*)&sE[side][rowA * 64 + (kcol ^ ((rowA & 7) << 3))];
      #pragma unroll
      for (int nt = 0; nt < 4; ++nt) {
        const int rowB = 16 * nt + r;
        const bf16x8 bh = *(const bf16x8*)&sUGh[rowB * 64 + (kcol ^ ((rowB & 7) << 3))];
        acc[nt] = __builtin_amdgcn_mfma_f32_16x16x32_bf16(ah, bh, acc[nt], 0, 0, 0);
      }
    }
    #pragma unroll
    for (int nt = 0; nt < 4; ++nt) {
      float zp = 0.f;
      #pragma unroll
      for (int reg = 0; reg < 4; ++reg) {
        const int kS = 16 * sub + 4 * g + reg;
        const int iS = 16 * nt + r;
        zp += bf2f(sUGh[iS * 64 + (kS ^ ((iS & 7) << 3))]) * acc[nt][reg];
      }
      zp += __shfl_xor(zp, 16);
      zp += __shfl_xor(zp, 32);
      if (g == 0) zpart[side][sub][16 * nt + r] = zp;
    }
  }
  __syncthreads();

  // ---- P5: combine + write ----
  if (t < 128) {
    const int side = t >> 6, c = t & 63;
    const float z2 = zpart[side][0][c] + zpart[side][1][c] +
                     zpart[side][2][c] + zpart[side][3][c];
    const float z1 = zp1[side][0][c] + zp1[side][1][c] +
                     zp1[side][2][c] + zp1[side][3][c];
    const int col = c * 32 + iT0 + side;
    out[b * 2048 + col] = h0[col] + z1 + z2;
  }
}

extern "C" void kernel_launch(void* const* d_in, const int* in_sizes, int n_in,
                              void* d_out, int out_size, void* d_ws, size_t ws_size,
                              hipStream_t stream) {
  const float* s   = (const float*)d_in[0];  // (16,2048)
  const float* UG  = (const float*)d_in[1];  // (64,64)
  const float* UPT = (const float*)d_in[2];  // (32,32)
  const float* h0  = (const float*)d_in[3];  // (2048,)
  const float* h1c = (const float*)d_in[4];  // (64,8)
  const float* HS  = (const float*)d_in[5];  // (64,64)
  const float* Hc  = (const float*)d_in[6];  // (8,8)
  float* out = (float*)d_out;

  volterra_one<<<256, 512, 0, stream>>>(s, UG, UPT, h0, h1c, HS, Hc, out);
}

// Round 10
// 13.348 us; speedup vs baseline: 1.1267x; 1.0274x over previous
//
#include <hip/hip_runtime.h>

// GraphVolterraLayer: N_S=64, N_T=32, N_EFF=2048, K_T1=K_T2=8, BATCH=16.
// One kernel, grid 256 = (b, iT-pair), 512 threads (8 waves), 5 barriers.
//
//  P0: stage S^T/UG^T bf16 hi/lo (swz), UG hi (swz), UPT f32; raw side weights
//  P1: T1 = UG^T S (MFMA 3-term hi/lo) + weight fold w' = wR UPT^T
//  P3a: Gm/A/Q = T1 x w' (fp32 VALU); Gm,A -> bf16 hi/lo packs [64][8];
//       wv = rowreduce(h1c .* Q)
//  P3b: E = HS .* (A Gm^T) via ONE packed MFMA per 16x16 tile
//       (k-slots [Ah|Ah|Al|0] x [Gh|Gl|Gh|0] = AhGh+AhGl+AlGh); HS from L2;
//       E -> bf16 XOR-swz; z1 partials = UG^T wv (fp32)
//  P4: F = E UG^T (MFMA hi-only); z2[iS] = sum_kS UG[iS,kS] F[kS,iS]
//  P5: out = h0 + z1 + z2
// mfma: D[row][col] = sum_k A[row][k]*B[col][k]; D-layout col=l&15,
// row=4*(l>>4)+reg (m89; validated on-problem r6-r9).

typedef short  bf16x8 __attribute__((ext_vector_type(8)));
typedef float  f32x4  __attribute__((ext_vector_type(4)));
typedef unsigned short u16;

static __device__ __forceinline__ u16 f2bf(float f) {
  unsigned u = __float_as_uint(f);
  u = (u + 0x7fff + ((u >> 16) & 1)) >> 16;    // RNE
  return (u16)u;
}
static __device__ __forceinline__ float bf2f(u16 h) {
  return __uint_as_float(((unsigned)h) << 16);
}
static __device__ __forceinline__ float dot4(f32x4 a, f32x4 b) {
  return a.x * b.x + a.y * b.y + a.z * b.z + a.w * b.w;
}

__global__ __launch_bounds__(512) void volterra_one(
    const float* __restrict__ s, const float* __restrict__ UG,
    const float* __restrict__ UPT, const float* __restrict__ h0,
    const float* __restrict__ h1c, const float* __restrict__ HS,
    const float* __restrict__ Hc, float* __restrict__ out)
{
  const int b   = blockIdx.x >> 4;
  const int iT0 = (blockIdx.x & 15) << 1;
  const int t   = threadIdx.x;
  const int w   = t >> 6;            // wave 0..7
  const int l   = t & 63;
  const int r   = l & 15;
  const int g   = l >> 4;

  __shared__ __align__(16) u16   sSTh[2048], sSTl[2048];   // S^T [32][64] swz
  __shared__ __align__(16) u16   sUGTh[4096], sUGTl[4096]; // UG^T [64][64] swz
  __shared__ __align__(16) u16   sUGh[4096];               // UG [64][64] swz hi
  __shared__ __align__(16) float sUPT[32][36];
  __shared__ __align__(16) float wGmR[2][288], wAR[2][288], wQR[2][288];
  __shared__ __align__(16) float wGmP[2][288], wAP[2][288], wQP[2][288];
  __shared__ __align__(16) float sT1[64][36];
  __shared__ __align__(16) u16   sGh[2][64][8], sGl[2][64][8];  // Gm hi/lo packs
  __shared__ __align__(16) u16   sAh[2][64][8], sAl[2][64][8];  // A  hi/lo packs
  __shared__ __align__(16) u16   szero16[8];               // 16B of zeros
  __shared__ __align__(16) u16   sE[2][4096];
  __shared__ float wv[2][64];
  __shared__ float zp1[2][4][64], zpart[2][4][64];

  // ---- P0: stage ----
  {  // S^T bf16 hi/lo, chunk-XOR swizzled
    const f32x4 v = ((const f32x4*)(s + b * 2048))[t];
    const int rr = t >> 3, c0 = (t & 7) * 4;
    const float arr[4] = {v.x, v.y, v.z, v.w};
    #pragma unroll
    for (int i = 0; i < 4; ++i) {
      const int c = c0 + i;
      const u16 hi = f2bf(arr[i]);
      const int ad = c * 64 + (((rr >> 3) ^ (c & 7)) << 3) + (rr & 7);
      sSTh[ad] = hi;
      sSTl[ad] = f2bf(arr[i] - bf2f(hi));
    }
  }
  #pragma unroll
  for (int it = 0; it < 2; ++it) {   // UG: row-major hi + transposed hi/lo
    const int o4 = t + it * 512;
    const int rr = o4 >> 4, c0 = (o4 & 15) * 4;
    const f32x4 v = ((const f32x4*)UG)[o4];
    const float arr[4] = {v.x, v.y, v.z, v.w};
    short4 h4;
    h4.x = (short)f2bf(v.x); h4.y = (short)f2bf(v.y);
    h4.z = (short)f2bf(v.z); h4.w = (short)f2bf(v.w);
    *(short4*)&sUGh[rr * 64 + (c0 ^ ((rr & 7) << 3))] = h4;
    #pragma unroll
    for (int i = 0; i < 4; ++i) {
      const int c = c0 + i;
      const u16 hi = f2bf(arr[i]);
      const int ad = c * 64 + (((rr >> 3) ^ (c & 7)) << 3) + (rr & 7);
      sUGTh[ad] = hi;
      sUGTl[ad] = f2bf(arr[i] - bf2f(hi));
    }
  }
  if (t < 256) {                     // UPT fp32
    *(f32x4*)&sUPT[t >> 3][(t & 7) * 4] = ((const f32x4*)UPT)[t];
  }
  if (t < 8) szero16[t] = 0;
  {                                  // raw per-side weights (global reads only)
    const int side = t >> 8, p = (t >> 5) & 7, k = t & 31;
    const int iTs = iT0 + side;
    const float m1 = UPT[iTs * 32 + k];
    const float m3 = UPT[k * 32 + iTs];
    const float m2 = UPT[k * 32 + p];
    float uh = 0.f;
    #pragma unroll
    for (int q = 0; q < 8; ++q) uh += UPT[k * 32 + q] * Hc[q * 8 + p];
    wGmR[side][p * 36 + k] = m1 * m2;
    wAR [side][p * 36 + k] = m1 * uh;
    wQR [side][p * 36 + k] = m3 * m2;
  }
  __syncthreads();

  // ---- P1: T1 = UG^T S (8 wave-tiles, LDS b128 frags) + weight fold ----
  {
    const int band = w >> 1, ct = w & 1;
    const int rowA = 16 * band + r, rowB = ct * 16 + r;
    f32x4 acc = {0.f, 0.f, 0.f, 0.f};
    #pragma unroll
    for (int kc = 0; kc < 2; ++kc) {
      const int ch = kc * 4 + g;
      const int oa = rowA * 64 + ((ch ^ (rowA & 7)) << 3);
      const int ob = rowB * 64 + ((ch ^ (rowB & 7)) << 3);
      const bf16x8 Ah = *(const bf16x8*)&sUGTh[oa];
      const bf16x8 Al = *(const bf16x8*)&sUGTl[oa];
      const bf16x8 Bh = *(const bf16x8*)&sSTh[ob];
      const bf16x8 Bl = *(const bf16x8*)&sSTl[ob];
      acc = __builtin_amdgcn_mfma_f32_16x16x32_bf16(Ah, Bh, acc, 0, 0, 0);
      acc = __builtin_amdgcn_mfma_f32_16x16x32_bf16(Ah, Bl, acc, 0, 0, 0);
      acc = __builtin_amdgcn_mfma_f32_16x16x32_bf16(Al, Bh, acc, 0, 0, 0);
    }
    #pragma unroll
    for (int reg = 0; reg < 4; ++reg)
      sT1[16 * band + 4 * g + reg][ct * 16 + r] = acc[reg];
  }
  {  // w'[p][j] = sum_k UPT[j,k] * wR[p][k]   (VALU, overlaps MFMA)
    const int side = t >> 8, p = (t >> 5) & 7, j = t & 31;
    float aG = 0.f, aA = 0.f, aQ = 0.f;
    #pragma unroll
    for (int k4 = 0; k4 < 8; ++k4) {
      const f32x4 u  = *(const f32x4*)&sUPT[j][k4 * 4];
      const f32x4 w1 = *(const f32x4*)&wGmR[side][p * 36 + k4 * 4];
      const f32x4 w2 = *(const f32x4*)&wAR [side][p * 36 + k4 * 4];
      const f32x4 w3 = *(const f32x4*)&wQR [side][p * 36 + k4 * 4];
      aG += dot4(u, w1); aA += dot4(u, w2); aQ += dot4(u, w3);
    }
    wGmP[side][p * 36 + j] = aG;
    wAP [side][p * 36 + j] = aA;
    wQP [side][p * 36 + j] = aQ;
  }
  __syncthreads();

  // ---- P3a: Gm/A/Q = T1 x w' (fp32) -> bf16 hi/lo packs + wv reduce ----
  {
    const int side = t >> 8, ts = t & 255;
    const int kSa = ts >> 3, p = ts & 7;
    float g0 = 0.f, g1v = 0.f, a0 = 0.f, a1v = 0.f, q0 = 0.f, q1v = 0.f;
    #pragma unroll
    for (int c4 = 0; c4 < 8; ++c4) {
      const f32x4 w1 = *(const f32x4*)&wGmP[side][p * 36 + c4 * 4];
      const f32x4 w2 = *(const f32x4*)&wAP [side][p * 36 + c4 * 4];
      const f32x4 w3 = *(const f32x4*)&wQP [side][p * 36 + c4 * 4];
      const f32x4 x0 = *(const f32x4*)&sT1[kSa][c4 * 4];
      const f32x4 x1 = *(const f32x4*)&sT1[kSa + 32][c4 * 4];
      g0  += dot4(x0, w1); a0  += dot4(x0, w2); q0  += dot4(x0, w3);
      g1v += dot4(x1, w1); a1v += dot4(x1, w2); q1v += dot4(x1, w3);
    }
    const u16 gh0 = f2bf(g0);
    sGh[side][kSa][p] = gh0;       sGl[side][kSa][p] = f2bf(g0 - bf2f(gh0));
    const u16 gh1 = f2bf(g1v);
    sGh[side][kSa + 32][p] = gh1;  sGl[side][kSa + 32][p] = f2bf(g1v - bf2f(gh1));
    const u16 ah0 = f2bf(a0);
    sAh[side][kSa][p] = ah0;       sAl[side][kSa][p] = f2bf(a0 - bf2f(ah0));
    const u16 ah1 = f2bf(a1v);
    sAh[side][kSa + 32][p] = ah1;  sAl[side][kSa + 32][p] = f2bf(a1v - bf2f(ah1));
    float wv0 = h1c[kSa * 8 + p] * q0;
    float wv1 = h1c[(kSa + 32) * 8 + p] * q1v;
    wv0 += __shfl_xor(wv0, 1); wv0 += __shfl_xor(wv0, 2); wv0 += __shfl_xor(wv0, 4);
    wv1 += __shfl_xor(wv1, 1); wv1 += __shfl_xor(wv1, 2); wv1 += __shfl_xor(wv1, 4);
    if (p == 0) { wv[side][kSa] = wv0; wv[side][kSa + 32] = wv1; }
  }
  __syncthreads();

  // ---- P3b: E = HS .* (A Gm^T) via packed MFMA; z1 partials ----
  {
    const int side = t >> 8, sub = (t >> 6) & 3;
    // A-frag k-slots [Ah|Ah|Al|0], B-frag [Gh|Gl|Gh|0] -> AhGh+AhGl+AlGh
    const int rowA = 16 * sub + r;
    const u16* ap = (g < 2)  ? &sAh[side][rowA][0]
                  : (g == 2) ? &sAl[side][rowA][0] : szero16;
    const bf16x8 af = *(const bf16x8*)ap;
    #pragma unroll
    for (int cb = 0; cb < 4; ++cb) {
      const int rowB = 16 * cb + r;
      const u16* bp = (g == 0) ? &sGh[side][rowB][0]
                    : (g == 1) ? &sGl[side][rowB][0]
                    : (g == 2) ? &sGh[side][rowB][0] : szero16;
      const bf16x8 bf = *(const bf16x8*)bp;
      f32x4 acc = {0.f, 0.f, 0.f, 0.f};
      acc = __builtin_amdgcn_mfma_f32_16x16x32_bf16(af, bf, acc, 0, 0, 0);
      #pragma unroll
      for (int reg = 0; reg < 4; ++reg) {
        const int row = 16 * sub + 4 * g + reg;
        const int col = 16 * cb + r;
        const float e = acc[reg] * HS[row * 64 + col];   // L2-hot global
        sE[side][row * 64 + (col ^ ((row & 7) << 3))] = f2bf(e);
      }
    }
    const float wvl = wv[side][l];
    float part = 0.f;
    #pragma unroll
    for (int j = 0; j < 16; ++j) {
      const int kk = 16 * sub + j;
      part += __shfl(wvl, kk) * UG[kk * 64 + l];         // exact fp32, L2-hot
    }
    zp1[side][sub][l] = part;
  }
  __syncthreads();

  // ---- P4: F = E UG^T (MFMA hi-only); fuse z2 ----
  {
    const int side = t >> 8, sub = (t >> 6) & 3;
    f32x4 acc[4];
    #pragma unroll
    for (int nt = 0; nt < 4; ++nt) acc[nt] = (f32x4){0.f, 0.f, 0.f, 0.f};
    #pragma unroll
    for (int ks = 0; ks < 2; ++ks) {
      const int kcol = g * 8 + ks * 32;
      const int rowA = 16 * sub + r;
      const bf16x8 ah = *(const bf16x8*)&sE[side][rowA * 64 + (kcol ^ ((rowA & 7) << 3))];
      #pragma unroll
      for (int nt = 0; nt < 4; ++nt) {
        const int rowB = 16 * nt + r;
        const bf16x8 bh = *(const bf16x8*)&sUGh[rowB * 64 + (kcol ^ ((rowB & 7) << 3))];
        acc[nt] = __builtin_amdgcn_mfma_f32_16x16x32_bf16(ah, bh, acc[nt], 0, 0, 0);
      }
    }
    #pragma unroll
    for (int nt = 0; nt < 4; ++nt) {
      float zp = 0.f;
      #pragma unroll
      for (int reg = 0; reg < 4; ++reg) {
        const int kS = 16 * sub + 4 * g + reg;
        const int iS = 16 * nt + r;
        zp += bf2f(sUGh[iS * 64 + (kS ^ ((iS & 7) << 3))]) * acc[nt][reg];
      }
      zp += __shfl_xor(zp, 16);
      zp += __shfl_xor(zp, 32);
      if (g == 0) zpart[side][sub][16 * nt + r] = zp;
    }
  }
  __syncthreads();

  // ---- P5: combine + write ----
  if (t < 128) {
    const int side = t >> 6, c = t & 63;
    const float z2 = zpart[side][0][c] + zpart[side][1][c] +
                     zpart[side][2][c] + zpart[side][3][c];
    const float z1 = zp1[side][0][c] + zp1[side][1][c] +
                     zp1[side][2][c] + zp1[side][3][c];
    const int col = c * 32 + iT0 + side;
    out[b * 2048 + col] = h0[col] + z1 + z2;
  }
}

extern "C" void kernel_launch(void* const* d_in, const int* in_sizes, int n_in,
                              void* d_out, int out_size, void* d_ws, size_t ws_size,
                              hipStream_t stream) {
  const float* s   = (const float*)d_in[0];  // (16,2048)
  const float* UG  = (const float*)d_in[1];  // (64,64)
  const float* UPT = (const float*)d_in[2];  // (32,32)
  const float* h0  = (const float*)d_in[3];  // (2048,)
  const float* h1c = (const float*)d_in[4];  // (64,8)
  const float* HS  = (const float*)d_in[5];  // (64,64)
  const float* Hc  = (const float*)d_in[6];  // (8,8)
  float* out = (float*)d_out;

  volterra_one<<<256, 512, 0, stream>>>(s, UG, UPT, h0, h1c, HS, Hc, out);
}